// Round 15
// baseline (97.618 us; speedup 1.0000x reference)
//
#include <hip/hip_runtime.h>
#include <math.h>

#define B_    64
#define N_    512
#define SEM_  256
#define STR_  256
#define DIM_  512              // SEM+STR
#define ROWS_ (B_*N_)          // 32768

// ---- workspace layout (float offsets) ----
#define OFF_QT16   0           // 256x256 bf16, Qt[e][d] = Q[d][e]
#define OFF_W116   32768       // 256x256 bf16, W116[o][d] = Wfz[o][d]
#define OFF_W2T    65536       // 256x256 f32, W2t[d][o] = Wfz[o][256+d]
#define OFF_V1     131072      // 256  Wfz2 @ exparam
#define OFF_C1     131328      // 256
#define OFF_C0     131584      // 1 (padded)
#define OFF_EV     131648      // 32768
#define OFF_FV     164416      // 32768
#define OFF_SUMP   197184      // 512*256 per-block partial sums
#define OFF_V2B    328256      // 64*256
#define OFF_ROW0   344640      // 64*256 pre-ReLU row-0 GEMM results

typedef __bf16 bf16x8 __attribute__((ext_vector_type(8)));
typedef float  f32x4  __attribute__((ext_vector_type(4)));

__device__ __forceinline__ ushort f2b(float x) {
    return __builtin_bit_cast(ushort, (__bf16)x);   // native v_cvt (RTNE)
}
__device__ __forceinline__ float bflo(unsigned u) {
    return __builtin_bit_cast(float, u << 16);
}
__device__ __forceinline__ float bfhi(unsigned u) {
    return __builtin_bit_cast(float, u & 0xffff0000u);
}

// ============ K0 (fused prep): Qt16, W116, W2t, v1, c1, c0 ============
__global__ __launch_bounds__(256) void k0(
    const float* __restrict__ Wp, const float* __restrict__ bp,
    const float* __restrict__ Wbil, const float* __restrict__ Wfz,
    const float* __restrict__ exparam,
    ushort* __restrict__ Qt16, ushort* __restrict__ W116, float* __restrict__ W2t,
    float* __restrict__ v1, float* __restrict__ c1, float* __restrict__ c0)
{
    __shared__ float Msh[256];
    __shared__ float g2sh[256];
    __shared__ float red[256];
    __shared__ float redB[256];
    int t = threadIdx.x, d0 = blockIdx.x;

    float mc = 0.f, g2 = 0.f;
#pragma unroll 32
    for (int a = 0; a < 256; ++a) {
        float wv = Wbil[a*256 + t];          // coalesced
        mc += Wp[a*256 + d0] * wv;           // broadcast
        g2 += bp[a] * wv;
    }
    Msh[t] = mc;
    g2sh[t] = g2;

    W116[d0*256 + t] = f2b(Wfz[d0*512 + t]);
    W2t[t*256 + d0] = Wfz[d0*512 + 256 + t];
    if (d0 == 0) {
        float s = 0.f;
        const float* w2 = Wfz + t*512 + 256;
#pragma unroll 32
        for (int dd = 0; dd < 256; ++dd) s += w2[dd] * exparam[dd];
        v1[t] = s;
    }
    __syncthreads();

    float q = 0.f;
#pragma unroll 32
    for (int c = 0; c < 256; ++c) q += Msh[c] * Wp[c*256 + t];   // coalesced
    Qt16[t*256 + d0] = f2b(q);               // transposed store (e-major)

    red[t]  = Msh[t]*bp[t] + Wp[t*256 + d0]*g2sh[t];
    redB[t] = g2sh[t]*bp[t];
    __syncthreads();
    for (int s2 = 128; s2 > 0; s2 >>= 1) {
        if (t < s2) { red[t] += red[t + s2]; redB[t] += redB[t + s2]; }
        __syncthreads();
    }
    if (t == 0) {
        c1[d0] = red[0];
        if (d0 == 0) c0[0] = redB[0];
    }
}

// ============ K1: MFMA GEMM u = str@Q -> Ev, fv via diag-MFMA ============
// 512 threads / 8 waves; distance-2 register B-prefetch (full-iter vmcnt slack).
__global__ __launch_bounds__(512, 4) void k_rowstats(
    const float* __restrict__ input, const ushort* __restrict__ Qt16,
    const float* __restrict__ c1, const float* __restrict__ c0,
    const float* __restrict__ Wfi, const float* __restrict__ bbil,
    const float* __restrict__ bfi, const float* __restrict__ W2t,
    float* __restrict__ Ev, float* __restrict__ fv, float* __restrict__ v2b)
{
    __shared__ __align__(16) char smem[73728];
    ushort* Ash   = (ushort*)smem;              // [64][256] bf16, XOR-swizzled
    ushort* Bsm0  = (ushort*)(smem + 32768);    // [256][40] bf16 (dbuf 0)
    ushort* Bsm1  = (ushort*)(smem + 53248);    // [256][40] bf16 (dbuf 1)
    ushort* Ush   = (ushort*)(smem + 32768);    // [64][256] bf16 swz (epilogue overlay)
    float*  sdiag = (float*)(smem + 65536);     // [64][8]
    float*  fdiag = (float*)(smem + 67584);     // [64][8]
    float*  s0sh  = (float*)(smem + 69632);     // [256]
    float*  shE0  = (float*)(smem + 70656);

    int t = threadIdx.x;
    int lane = t & 63, w = t >> 6;               // 8 waves
    int g = lane >> 4, li = lane & 15;
    long rowbase = (long)blockIdx.x * 64;
    int b = (int)(rowbase >> 9);
    int i0 = (int)(rowbase & 511);
    const float* Ab = input + rowbase*DIM_ + SEM_;   // str half
    int xs = (li & 7) << 3;
    int bn = (t + 0) >> 2, bc = t & 3;           // B-stage indices (q=0)
    int bn1 = (t + 512) >> 2;                    // q=1

    // stage A (str) tile: fp32 -> bf16, swizzled
#pragma unroll
    for (int q = 0; q < 8; ++q) {
        int v = t + 512*q;
        int r = v >> 6, c4 = v & 63;
        float4 a4 = *(const float4*)(Ab + (long)r*DIM_ + c4*4);
        ushort4 b4 = make_ushort4(f2b(a4.x), f2b(a4.y), f2b(a4.z), f2b(a4.w));
        *(ushort4*)&Ash[r*256 + ((c4*4) ^ ((r & 7) << 3))] = b4;
    }
    // prologue: stage slice 0 direct; load slice 1 into regs
    uint4 bregA[2];
    *(uint4*)&Bsm0[bn*40 + bc*8]  = *(const uint4*)&Qt16[bn*256 + bc*8];
    *(uint4*)&Bsm0[bn1*40 + bc*8] = *(const uint4*)&Qt16[bn1*256 + bc*8];
    bregA[0] = *(const uint4*)&Qt16[bn*256 + 32 + bc*8];
    bregA[1] = *(const uint4*)&Qt16[bn1*256 + 32 + bc*8];
    __syncthreads();

    f32x4 acc[4][2];
#pragma unroll
    for (int m = 0; m < 4; ++m)
#pragma unroll
        for (int n = 0; n < 2; ++n) acc[m][n] = (f32x4){0.f, 0.f, 0.f, 0.f};

#pragma unroll
    for (int ks = 0; ks < 8; ++ks) {
        ushort* Bcur = (ks & 1) ? Bsm1 : Bsm0;
        ushort* Bnxt = (ks & 1) ? Bsm0 : Bsm1;
        int k0v = ks*32;
        uint4 bregB[2];
        if (ks < 6) {   // issue loads for slice ks+2 (landed by iter ks+1)
            bregB[0] = *(const uint4*)&Qt16[bn*256 + (k0v + 64) + bc*8];
            bregB[1] = *(const uint4*)&Qt16[bn1*256 + (k0v + 64) + bc*8];
        }
        if (ks < 7) {   // write slice ks+1 (loaded a full iteration ago)
            *(uint4*)&Bnxt[bn*40 + bc*8]  = bregA[0];
            *(uint4*)&Bnxt[bn1*40 + bc*8] = bregA[1];
        }
        bf16x8 af[4], bfr[2];
#pragma unroll
        for (int m = 0; m < 4; ++m)
            af[m] = *(const bf16x8*)&Ash[(m*16 + li)*256 + ((k0v + g*8) ^ xs)];
#pragma unroll
        for (int n = 0; n < 2; ++n)
            bfr[n] = *(const bf16x8*)&Bcur[(w*32 + n*16 + li)*40 + g*8];
#pragma unroll
        for (int m = 0; m < 4; ++m)
#pragma unroll
            for (int n = 0; n < 2; ++n)
                acc[m][n] = __builtin_amdgcn_mfma_f32_16x16x32_bf16(af[m], bfr[n], acc[m][n], 0, 0, 0);
        if (ks < 6) { bregA[0] = bregB[0]; bregA[1] = bregB[1]; }
        __syncthreads();
    }

    // ---- U' = u + c1 -> Ush (bf16, swizzled); Bsm dead ----
    float c1v[2];
#pragma unroll
    for (int n = 0; n < 2; ++n) c1v[n] = c1[w*32 + n*16 + li];
#pragma unroll
    for (int m = 0; m < 4; ++m)
#pragma unroll
        for (int n = 0; n < 2; ++n)
#pragma unroll
            for (int reg = 0; reg < 4; ++reg) {
                int row = m*16 + g*4 + reg;
                int col = w*32 + n*16 + li;
                Ush[row*256 + (col ^ ((row & 7) << 3))] = f2b(acc[m][n][reg] + c1v[n]);
            }
    __syncthreads();

    // ---- diag MFMA: s = diag(U' @ Str^T), f = Wfi-broadcast; one K-step per wave ----
    f32x4 dacc[4], facc[4];
#pragma unroll
    for (int m = 0; m < 4; ++m) { dacc[m] = (f32x4){0.f,0.f,0.f,0.f}; facc[m] = (f32x4){0.f,0.f,0.f,0.f}; }
    {
        int kb = w*32 + g*8;                    // 8 waves cover K=256
        float4 wf0 = *(const float4*)(Wfi + kb);
        float4 wf1 = *(const float4*)(Wfi + kb + 4);
        bf16x8 afw = (bf16x8){(__bf16)wf0.x, (__bf16)wf0.y, (__bf16)wf0.z, (__bf16)wf0.w,
                              (__bf16)wf1.x, (__bf16)wf1.y, (__bf16)wf1.z, (__bf16)wf1.w};
#pragma unroll
        for (int m = 0; m < 4; ++m) {
            int ridx = (m*16 + li)*256 + (kb ^ xs);
            bf16x8 afu = *(const bf16x8*)&Ush[ridx];
            bf16x8 bfs = *(const bf16x8*)&Ash[ridx];
            dacc[m] = __builtin_amdgcn_mfma_f32_16x16x32_bf16(afu, bfs, dacc[m], 0, 0, 0);
            facc[m] = __builtin_amdgcn_mfma_f32_16x16x32_bf16(afw, bfs, facc[m], 0, 0, 0);
        }
    }
    // diag extraction: lane owns D[row=g*4+reg][col=li]; diag when li == g*4+reg
    if (g == (li >> 2)) {
        int dr = li & 3;
#pragma unroll
        for (int m = 0; m < 4; ++m) {
            float dv = dr == 0 ? dacc[m][0] : dr == 1 ? dacc[m][1] : dr == 2 ? dacc[m][2] : dacc[m][3];
            sdiag[(m*16 + li)*8 + w] = dv;
        }
    }
    if (g == 0) {
#pragma unroll
        for (int m = 0; m < 4; ++m) fdiag[(m*16 + li)*8 + w] = facc[m][0];
    }
    __syncthreads();
    if (t < 64) {
        float ss = 0.f, ff = 0.f;
#pragma unroll
        for (int j = 0; j < 8; ++j) { ss += sdiag[t*8 + j]; ff += fdiag[t*8 + j]; }
        float ev = expf(ss + c0[0] + bbil[0]);
        Ev[rowbase + t] = ev;
        fv[rowbase + t] = expf(ff + bfi[0]);
        if (t == 0) shE0[0] = ev;
    }

    // v2b for the block owning batch row 0
    if (i0 == 0) {
        if (t < 64)
            *(float4*)&s0sh[t*4] = *(const float4*)(input + (long)b*512*DIM_ + t*4);
        __syncthreads();
        if (t < 256) {
            float a2 = 0.f;
#pragma unroll 16
            for (int d = 0; d < 256; ++d) a2 += W2t[d*256 + t] * s0sh[d];
            v2b[b*256 + t] = shE0[0] * a2;
        }
    }
}

// ============ K3: MFMA GEMM sem@Wfz1^T + direct-store epilogue + sump ============
// 512 threads / 8 waves; distance-2 register B-prefetch.
__global__ __launch_bounds__(512, 4) void k_final(
    const float* __restrict__ input, const ushort* __restrict__ W116,
    const float* __restrict__ v1, const float* __restrict__ v2b,
    const float* __restrict__ Ev, const float* __restrict__ fv,
    const float* __restrict__ bfz,
    float* __restrict__ sump, float* __restrict__ row0pre,
    float* __restrict__ out)
{
    __shared__ __align__(16) char smem[74560];
    ushort* Ash    = (ushort*)smem;             // [64][256] bf16 swz
    ushort* Bsm0   = (ushort*)(smem + 32768);   // [256][40] (dbuf 0)
    ushort* Bsm1   = (ushort*)(smem + 53248);   // [256][40] (dbuf 1)
    float*  sumred = (float*)(smem + 36864);    // [16][256] f32 (post-loop overlay)
    float*  cAs    = (float*)(smem + 73728);    // 64
    float*  cBs    = (float*)(smem + 73984);    // 64
    float*  EvL    = (float*)(smem + 74240);    // 64
    float*  wred   = (float*)(smem + 74496);    // 8

    int t = threadIdx.x;
    int lane = t & 63, w = t >> 6;               // 8 waves
    int g = lane >> 4, li = lane & 15;
    long rowbase = (long)blockIdx.x * 64;
    int b = (int)(rowbase >> 9);
    int i0 = (int)(rowbase & 511);
    const float* Ab = input + rowbase*DIM_;          // sem half
    int xs = (li & 7) << 3;
    int bn = (t + 0) >> 2, bc = t & 3;
    int bn1 = (t + 512) >> 2;

    // Fws = sum fv over batch via wave-shuffle reduce (512 threads, 1 elem each)
    float fsum = fv[b*512 + t];
#pragma unroll
    for (int off = 32; off >= 1; off >>= 1) fsum += __shfl_down(fsum, off);
    if (lane == 0) wred[w] = fsum;
    __syncthreads();
    float invF = 1.0f / (wred[0] + wred[1] + wred[2] + wred[3]
                       + wred[4] + wred[5] + wred[6] + wred[7]);

    if (t < 64) {
        int row = (int)rowbase + t;
        float fr = fv[row];
        float ev = Ev[row];
        EvL[t] = (i0 == 0 && t == 0) ? 0.f : ev;     // exclude j=0 from sump
        cAs[t] = fr * invF;                          // d0
        cBs[t] = ((i0 + t) == 0) ? -invF
               : (1.0f + (fv[b*512] - fr)*invF) / (512.0f * ev);
    }

    // stage A (sem) tile, swizzled
#pragma unroll
    for (int q = 0; q < 8; ++q) {
        int v = t + 512*q;
        int r = v >> 6, c4 = v & 63;
        float4 a4 = *(const float4*)(Ab + (long)r*DIM_ + c4*4);
        ushort4 b4 = make_ushort4(f2b(a4.x), f2b(a4.y), f2b(a4.z), f2b(a4.w));
        *(ushort4*)&Ash[r*256 + ((c4*4) ^ ((r & 7) << 3))] = b4;
    }
    // prologue: stage slice 0 direct; load slice 1 into regs
    uint4 bregA[2];
    *(uint4*)&Bsm0[bn*40 + bc*8]  = *(const uint4*)&W116[bn*256 + bc*8];
    *(uint4*)&Bsm0[bn1*40 + bc*8] = *(const uint4*)&W116[bn1*256 + bc*8];
    bregA[0] = *(const uint4*)&W116[bn*256 + 32 + bc*8];
    bregA[1] = *(const uint4*)&W116[bn1*256 + 32 + bc*8];
    __syncthreads();

    f32x4 acc[4][2];
#pragma unroll
    for (int m = 0; m < 4; ++m)
#pragma unroll
        for (int n = 0; n < 2; ++n) acc[m][n] = (f32x4){0.f, 0.f, 0.f, 0.f};

#pragma unroll
    for (int ks = 0; ks < 8; ++ks) {
        ushort* Bcur = (ks & 1) ? Bsm1 : Bsm0;
        ushort* Bnxt = (ks & 1) ? Bsm0 : Bsm1;
        int k0v = ks*32;
        uint4 bregB[2];
        if (ks < 6) {
            bregB[0] = *(const uint4*)&W116[bn*256 + (k0v + 64) + bc*8];
            bregB[1] = *(const uint4*)&W116[bn1*256 + (k0v + 64) + bc*8];
        }
        if (ks < 7) {
            *(uint4*)&Bnxt[bn*40 + bc*8]  = bregA[0];
            *(uint4*)&Bnxt[bn1*40 + bc*8] = bregA[1];
        }
        bf16x8 af[4], bfr[2];
#pragma unroll
        for (int m = 0; m < 4; ++m)
            af[m] = *(const bf16x8*)&Ash[(m*16 + li)*256 + ((k0v + g*8) ^ xs)];
#pragma unroll
        for (int n = 0; n < 2; ++n)
            bfr[n] = *(const bf16x8*)&Bcur[(w*32 + n*16 + li)*40 + g*8];
#pragma unroll
        for (int m = 0; m < 4; ++m)
#pragma unroll
            for (int n = 0; n < 2; ++n)
                acc[m][n] = __builtin_amdgcn_mfma_f32_16x16x32_bf16(af[m], bfr[n], acc[m][n], 0, 0, 0);
        if (ks < 6) { bregA[0] = bregB[0]; bregA[1] = bregB[1]; }
        __syncthreads();
    }

    // ---- sump partial: sum_{j in block, j!=0} Ev_j * sem[j][d] ----
    {
        int qq = t >> 5, c8 = t & 31;           // 16 groups x 4 rows
        float p[8];
#pragma unroll
        for (int i = 0; i < 8; ++i) p[i] = 0.f;
#pragma unroll
        for (int rr = 0; rr < 4; ++rr) {
            int r = qq*4 + rr;
            float ev = EvL[r];
            uint4 uv = *(const uint4*)&Ash[r*256 + ((c8*8) ^ ((r & 7) << 3))];
            p[0] += ev * bflo(uv.x); p[1] += ev * bfhi(uv.x);
            p[2] += ev * bflo(uv.y); p[3] += ev * bfhi(uv.y);
            p[4] += ev * bflo(uv.z); p[5] += ev * bfhi(uv.z);
            p[6] += ev * bflo(uv.w); p[7] += ev * bfhi(uv.w);
        }
        *(float4*)&sumred[qq*256 + c8*8]     = (float4){p[0], p[1], p[2], p[3]};
        *(float4*)&sumred[qq*256 + c8*8 + 4] = (float4){p[4], p[5], p[6], p[7]};
    }
    __syncthreads();
    if (t < 256) {
        float sp = 0.f;
#pragma unroll
        for (int qq = 0; qq < 16; ++qq) sp += sumred[qq*256 + t];
        sump[(long)blockIdx.x*256 + t] = sp;
    }

    // ---- direct-store epilogue (no LDS repack, no extra barriers) ----
    float v1v[2], v2v[2], bzv[2];
#pragma unroll
    for (int n = 0; n < 2; ++n) {
        int col = w*32 + n*16 + li;
        v1v[n] = v1[col];
        v2v[n] = v2b[b*256 + col];
        bzv[n] = bfz[col];
    }
#pragma unroll
    for (int m = 0; m < 4; ++m) {
#pragma unroll
        for (int reg = 0; reg < 4; ++reg) {
            int row = m*16 + g*4 + reg;
            float ca = cAs[row], cb = cBs[row];
            int irow = i0 + row;
#pragma unroll
            for (int n = 0; n < 2; ++n) {
                int col = w*32 + n*16 + li;
                float sel = (irow == 0) ? 0.f : v2v[n];
                float val = acc[m][n][reg] + ca*v1v[n] + cb*sel + bzv[n];
                if (irow == 0) row0pre[b*256 + col] = val;   // pre-ReLU, no v0 term
                out[(rowbase + row)*256 + col] = fmaxf(val, 0.f);
            }
        }
    }
}

// ============ K4: fixup row i=0 of each batch ============
__global__ __launch_bounds__(256) void k_fix(
    const float* __restrict__ sump, const float* __restrict__ fv,
    const float* __restrict__ W2t, const float* __restrict__ row0pre,
    float* __restrict__ out)
{
    int b = blockIdx.x, t = threadIdx.x;
    __shared__ float svsh[256];
    __shared__ float redF[256];
    float a = 0.f;
#pragma unroll
    for (int p = 0; p < 8; ++p) a += sump[(long)(b*8 + p)*256 + t];
    svsh[t] = a;
    redF[t] = fv[b*512 + t] + fv[b*512 + 256 + t];
    __syncthreads();
    for (int s2 = 128; s2 > 0; s2 >>= 1) {
        if (t < s2) redF[t] += redF[t + s2];
        __syncthreads();
    }
    float invF = 1.0f / redF[0];
    float a0 = 0.f;
#pragma unroll 16
    for (int d = 0; d < 256; ++d) a0 += W2t[d*256 + t] * svsh[d];
    out[((long)b*512)*256 + t] = fmaxf(row0pre[b*256 + t] - invF*a0, 0.f);
}

extern "C" void kernel_launch(void* const* d_in, const int* in_sizes, int n_in,
                              void* d_out, int out_size, void* d_ws, size_t ws_size,
                              hipStream_t stream) {
    const float* input   = (const float*)d_in[0];
    const float* Wp      = (const float*)d_in[1];
    const float* bp      = (const float*)d_in[2];
    const float* Wbil    = (const float*)d_in[3];
    const float* bbil    = (const float*)d_in[4];
    const float* Wfi     = (const float*)d_in[5];
    const float* bfi     = (const float*)d_in[6];
    const float* exparam = (const float*)d_in[7];
    const float* Wfz     = (const float*)d_in[8];
    const float* bfz     = (const float*)d_in[9];
    float* ws  = (float*)d_ws;
    float* out = (float*)d_out;

    ushort* Qt16  = (ushort*)(ws + OFF_QT16);
    ushort* W116  = (ushort*)(ws + OFF_W116);
    float*  W2t   = ws + OFF_W2T;
    float*  v1    = ws + OFF_V1;
    float*  c1    = ws + OFF_C1;
    float*  c0    = ws + OFF_C0;
    float*  Ev    = ws + OFF_EV;
    float*  fv    = ws + OFF_FV;
    float*  sump  = ws + OFF_SUMP;
    float*  v2b   = ws + OFF_V2B;
    float*  row0p = ws + OFF_ROW0;

    k0<<<256, 256, 0, stream>>>(Wp, bp, Wbil, Wfz, exparam, Qt16, W116, W2t, v1, c1, c0);
    k_rowstats<<<ROWS_/64, 512, 0, stream>>>(input, Qt16, c1, c0, Wfi, bbil, bfi, W2t, Ev, fv, v2b);
    k_final<<<ROWS_/64, 512, 0, stream>>>(input, W116, v1, v2b, Ev, fv, bfz, sump, row0p, out);
    k_fix<<<B_, 256, 0, stream>>>(sump, fv, W2t, row0p, out);
}

// Round 16
// 79.306 us; speedup vs baseline: 1.2309x; 1.2309x over previous
//
#include <hip/hip_runtime.h>
#include <math.h>

#define B_    64
#define N_    512
#define SEM_  256
#define STR_  256
#define DIM_  512              // SEM+STR
#define ROWS_ (B_*N_)          // 32768

// ---- workspace layout (float offsets) ----
#define OFF_QT16   0           // 256x256 bf16, Qt[e][d] = Q[d][e]
#define OFF_W116   32768       // 256x256 bf16, W116[o][d] = Wfz[o][d]
#define OFF_W2T    65536       // 256x256 f32, W2t[d][o] = Wfz[o][256+d]
#define OFF_V1     131072      // 256  Wfz2 @ exparam
#define OFF_C1     131328      // 256
#define OFF_C0     131584      // 1 (padded)
#define OFF_EV     131648      // 32768
#define OFF_FV     164416      // 32768
#define OFF_SUMP   197184      // 512*256 per-block partial sums
#define OFF_V2B    328256      // 64*256
#define OFF_ROW0   344640      // 64*256 pre-ReLU row-0 GEMM results

typedef __bf16 bf16x8 __attribute__((ext_vector_type(8)));
typedef float  f32x4  __attribute__((ext_vector_type(4)));

__device__ __forceinline__ ushort f2b(float x) {
    return __builtin_bit_cast(ushort, (__bf16)x);   // native v_cvt (RTNE)
}
__device__ __forceinline__ float bflo(unsigned u) {
    return __builtin_bit_cast(float, u << 16);
}
__device__ __forceinline__ float bfhi(unsigned u) {
    return __builtin_bit_cast(float, u & 0xffff0000u);
}

// ============ K0 (fused prep): Qt16, W116, W2t, v1, c1, c0 in ONE kernel ============
__global__ __launch_bounds__(256) void k0(
    const float* __restrict__ Wp, const float* __restrict__ bp,
    const float* __restrict__ Wbil, const float* __restrict__ Wfz,
    const float* __restrict__ exparam,
    ushort* __restrict__ Qt16, ushort* __restrict__ W116, float* __restrict__ W2t,
    float* __restrict__ v1, float* __restrict__ c1, float* __restrict__ c0)
{
    __shared__ float Msh[256];
    __shared__ float g2sh[256];
    __shared__ float red[256];
    __shared__ float redB[256];
    int t = threadIdx.x, d0 = blockIdx.x;

    float mc = 0.f, g2 = 0.f;
#pragma unroll 32
    for (int a = 0; a < 256; ++a) {
        float wv = Wbil[a*256 + t];          // coalesced
        mc += Wp[a*256 + d0] * wv;           // broadcast
        g2 += bp[a] * wv;
    }
    Msh[t] = mc;
    g2sh[t] = g2;

    W116[d0*256 + t] = f2b(Wfz[d0*512 + t]);
    W2t[t*256 + d0] = Wfz[d0*512 + 256 + t];
    if (d0 == 0) {
        float s = 0.f;
        const float* w2 = Wfz + t*512 + 256;
#pragma unroll 32
        for (int dd = 0; dd < 256; ++dd) s += w2[dd] * exparam[dd];
        v1[t] = s;
    }
    __syncthreads();

    float q = 0.f;
#pragma unroll 32
    for (int c = 0; c < 256; ++c) q += Msh[c] * Wp[c*256 + t];   // coalesced
    Qt16[t*256 + d0] = f2b(q);               // transposed store (e-major)

    red[t]  = Msh[t]*bp[t] + Wp[t*256 + d0]*g2sh[t];
    redB[t] = g2sh[t]*bp[t];
    __syncthreads();
    for (int s2 = 128; s2 > 0; s2 >>= 1) {
        if (t < s2) { red[t] += red[t + s2]; redB[t] += redB[t + s2]; }
        __syncthreads();
    }
    if (t == 0) {
        c1[d0] = red[0];
        if (d0 == 0) c0[0] = redB[0];
    }
}

// ============ K1: MFMA GEMM u = str@Q -> Ev, fv via diag-MFMA ============
// 512 threads / 8 waves per block; dbuf k-loop; 2 blocks/CU -> 16 waves/CU.
__global__ __launch_bounds__(512, 4) void k_rowstats(
    const float* __restrict__ input, const ushort* __restrict__ Qt16,
    const float* __restrict__ c1, const float* __restrict__ c0,
    const float* __restrict__ Wfi, const float* __restrict__ bbil,
    const float* __restrict__ bfi, const float* __restrict__ W2t,
    float* __restrict__ Ev, float* __restrict__ fv, float* __restrict__ v2b)
{
    __shared__ __align__(16) char smem[73728];
    ushort* Ash   = (ushort*)smem;              // [64][256] bf16, XOR-swizzled
    ushort* Bsm0  = (ushort*)(smem + 32768);    // [256][40] bf16 (dbuf 0)
    ushort* Bsm1  = (ushort*)(smem + 53248);    // [256][40] bf16 (dbuf 1)
    ushort* Ush   = (ushort*)(smem + 32768);    // [64][256] bf16 swz (epilogue overlay)
    float*  sdiag = (float*)(smem + 65536);     // [64][8]
    float*  fdiag = (float*)(smem + 67584);     // [64][8]
    float*  s0sh  = (float*)(smem + 69632);     // [256]
    float*  shE0  = (float*)(smem + 70656);

    int t = threadIdx.x;
    int lane = t & 63, w = t >> 6;               // 8 waves
    int g = lane >> 4, li = lane & 15;
    long rowbase = (long)blockIdx.x * 64;
    int b = (int)(rowbase >> 9);
    int i0 = (int)(rowbase & 511);
    const float* Ab = input + rowbase*DIM_ + SEM_;   // str half
    int xs = (li & 7) << 3;

    // stage A (str) tile: fp32 -> bf16, swizzled
#pragma unroll
    for (int q = 0; q < 8; ++q) {
        int v = t + 512*q;
        int r = v >> 6, c4 = v & 63;
        float4 a4 = *(const float4*)(Ab + (long)r*DIM_ + c4*4);
        ushort4 b4 = make_ushort4(f2b(a4.x), f2b(a4.y), f2b(a4.z), f2b(a4.w));
        *(ushort4*)&Ash[r*256 + ((c4*4) ^ ((r & 7) << 3))] = b4;
    }
    // prologue: stage B slice 0 (thread-linear, coalesced)
#pragma unroll
    for (int q = 0; q < 2; ++q) {
        int v = t + 512*q;
        int n = v >> 2, c = v & 3;
        *(uint4*)&Bsm0[n*40 + c*8] = *(const uint4*)&Qt16[n*256 + c*8];
    }
    __syncthreads();

    f32x4 acc[4][2];
#pragma unroll
    for (int m = 0; m < 4; ++m)
#pragma unroll
        for (int n = 0; n < 2; ++n) acc[m][n] = (f32x4){0.f, 0.f, 0.f, 0.f};

#pragma unroll
    for (int ks = 0; ks < 8; ++ks) {
        ushort* Bcur = (ks & 1) ? Bsm1 : Bsm0;
        ushort* Bnxt = (ks & 1) ? Bsm0 : Bsm1;
        int k0v = ks*32;
        uint4 breg[2];
        if (ks < 7) {   // issue next-slice loads early
#pragma unroll
            for (int q = 0; q < 2; ++q) {
                int v = t + 512*q;
                int n = v >> 2, c = v & 3;
                breg[q] = *(const uint4*)&Qt16[n*256 + (k0v + 32) + c*8];
            }
        }
        bf16x8 af[4], bfr[2];
#pragma unroll
        for (int m = 0; m < 4; ++m)
            af[m] = *(const bf16x8*)&Ash[(m*16 + li)*256 + ((k0v + g*8) ^ xs)];
#pragma unroll
        for (int n = 0; n < 2; ++n)
            bfr[n] = *(const bf16x8*)&Bcur[(w*32 + n*16 + li)*40 + g*8];
#pragma unroll
        for (int m = 0; m < 4; ++m)
#pragma unroll
            for (int n = 0; n < 2; ++n)
                acc[m][n] = __builtin_amdgcn_mfma_f32_16x16x32_bf16(af[m], bfr[n], acc[m][n], 0, 0, 0);
        if (ks < 7) {
#pragma unroll
            for (int q = 0; q < 2; ++q) {
                int v = t + 512*q;
                int n = v >> 2, c = v & 3;
                *(uint4*)&Bnxt[n*40 + c*8] = breg[q];
            }
        }
        __syncthreads();
    }

    // ---- U' = u + c1 -> Ush (bf16, swizzled); Bsm dead ----
    float c1v[2];
#pragma unroll
    for (int n = 0; n < 2; ++n) c1v[n] = c1[w*32 + n*16 + li];
#pragma unroll
    for (int m = 0; m < 4; ++m)
#pragma unroll
        for (int n = 0; n < 2; ++n)
#pragma unroll
            for (int reg = 0; reg < 4; ++reg) {
                int row = m*16 + g*4 + reg;
                int col = w*32 + n*16 + li;
                Ush[row*256 + (col ^ ((row & 7) << 3))] = f2b(acc[m][n][reg] + c1v[n]);
            }
    __syncthreads();

    // ---- diag MFMA: s = diag(U' @ Str^T), f = Wfi-broadcast; one K-step per wave ----
    f32x4 dacc[4], facc[4];
#pragma unroll
    for (int m = 0; m < 4; ++m) { dacc[m] = (f32x4){0.f,0.f,0.f,0.f}; facc[m] = (f32x4){0.f,0.f,0.f,0.f}; }
    {
        int kb = w*32 + g*8;                    // 8 waves cover K=256
        float4 wf0 = *(const float4*)(Wfi + kb);
        float4 wf1 = *(const float4*)(Wfi + kb + 4);
        bf16x8 afw = (bf16x8){(__bf16)wf0.x, (__bf16)wf0.y, (__bf16)wf0.z, (__bf16)wf0.w,
                              (__bf16)wf1.x, (__bf16)wf1.y, (__bf16)wf1.z, (__bf16)wf1.w};
#pragma unroll
        for (int m = 0; m < 4; ++m) {
            int ridx = (m*16 + li)*256 + (kb ^ xs);
            bf16x8 afu = *(const bf16x8*)&Ush[ridx];
            bf16x8 bfs = *(const bf16x8*)&Ash[ridx];
            dacc[m] = __builtin_amdgcn_mfma_f32_16x16x32_bf16(afu, bfs, dacc[m], 0, 0, 0);
            facc[m] = __builtin_amdgcn_mfma_f32_16x16x32_bf16(afw, bfs, facc[m], 0, 0, 0);
        }
    }
    // diag extraction: lane owns D[row=g*4+reg][col=li]; diag when li == g*4+reg
    if (g == (li >> 2)) {
        int dr = li & 3;
#pragma unroll
        for (int m = 0; m < 4; ++m) {
            float dv = dr == 0 ? dacc[m][0] : dr == 1 ? dacc[m][1] : dr == 2 ? dacc[m][2] : dacc[m][3];
            sdiag[(m*16 + li)*8 + w] = dv;
        }
    }
    if (g == 0) {
#pragma unroll
        for (int m = 0; m < 4; ++m) fdiag[(m*16 + li)*8 + w] = facc[m][0];
    }
    __syncthreads();
    if (t < 64) {
        float ss = 0.f, ff = 0.f;
#pragma unroll
        for (int j = 0; j < 8; ++j) { ss += sdiag[t*8 + j]; ff += fdiag[t*8 + j]; }
        float ev = expf(ss + c0[0] + bbil[0]);
        Ev[rowbase + t] = ev;
        fv[rowbase + t] = expf(ff + bfi[0]);
        if (t == 0) shE0[0] = ev;
    }

    // v2b for the block owning batch row 0
    if (i0 == 0) {
        if (t < 64)
            *(float4*)&s0sh[t*4] = *(const float4*)(input + (long)b*512*DIM_ + t*4);
        __syncthreads();
        if (t < 256) {
            float a2 = 0.f;
#pragma unroll 16
            for (int d = 0; d < 256; ++d) a2 += W2t[d*256 + t] * s0sh[d];
            v2b[b*256 + t] = shE0[0] * a2;
        }
    }
}

// ============ K3: MFMA GEMM sem@Wfz1^T + direct-store epilogue + sump ============
// 512 threads / 8 waves; dbuf k-loop; NO Csh repack (direct global stores).
__global__ __launch_bounds__(512, 4) void k_final(
    const float* __restrict__ input, const ushort* __restrict__ W116,
    const float* __restrict__ v1, const float* __restrict__ v2b,
    const float* __restrict__ Ev, const float* __restrict__ fv,
    const float* __restrict__ bfz,
    float* __restrict__ sump, float* __restrict__ row0pre,
    float* __restrict__ out)
{
    __shared__ __align__(16) char smem[74560];
    ushort* Ash    = (ushort*)smem;             // [64][256] bf16 swz
    ushort* Bsm0   = (ushort*)(smem + 32768);   // [256][40] (dbuf 0)
    ushort* Bsm1   = (ushort*)(smem + 53248);   // [256][40] (dbuf 1)
    float*  sumred = (float*)(smem + 36864);    // [16][256] f32 (post-loop overlay)
    float*  cAs    = (float*)(smem + 73728);    // 64
    float*  cBs    = (float*)(smem + 73984);    // 64
    float*  EvL    = (float*)(smem + 74240);    // 64
    float*  wred   = (float*)(smem + 74496);    // 8

    int t = threadIdx.x;
    int lane = t & 63, w = t >> 6;               // 8 waves
    int g = lane >> 4, li = lane & 15;
    long rowbase = (long)blockIdx.x * 64;
    int b = (int)(rowbase >> 9);
    int i0 = (int)(rowbase & 511);
    const float* Ab = input + rowbase*DIM_;          // sem half
    int xs = (li & 7) << 3;

    // Fws = sum fv over batch via wave-shuffle reduce (512 threads, 1 elem each)
    float fsum = fv[b*512 + t];
#pragma unroll
    for (int off = 32; off >= 1; off >>= 1) fsum += __shfl_down(fsum, off);
    if (lane == 0) wred[w] = fsum;
    __syncthreads();
    float invF = 1.0f / (wred[0] + wred[1] + wred[2] + wred[3]
                       + wred[4] + wred[5] + wred[6] + wred[7]);

    if (t < 64) {
        int row = (int)rowbase + t;
        float fr = fv[row];
        float ev = Ev[row];
        EvL[t] = (i0 == 0 && t == 0) ? 0.f : ev;     // exclude j=0 from sump
        cAs[t] = fr * invF;                          // d0
        cBs[t] = ((i0 + t) == 0) ? -invF
               : (1.0f + (fv[b*512] - fr)*invF) / (512.0f * ev);
    }

    // stage A (sem) tile, swizzled
#pragma unroll
    for (int q = 0; q < 8; ++q) {
        int v = t + 512*q;
        int r = v >> 6, c4 = v & 63;
        float4 a4 = *(const float4*)(Ab + (long)r*DIM_ + c4*4);
        ushort4 b4 = make_ushort4(f2b(a4.x), f2b(a4.y), f2b(a4.z), f2b(a4.w));
        *(ushort4*)&Ash[r*256 + ((c4*4) ^ ((r & 7) << 3))] = b4;
    }
    // prologue: stage B slice 0
#pragma unroll
    for (int q = 0; q < 2; ++q) {
        int v = t + 512*q;
        int n = v >> 2, c = v & 3;
        *(uint4*)&Bsm0[n*40 + c*8] = *(const uint4*)&W116[n*256 + c*8];
    }
    __syncthreads();

    f32x4 acc[4][2];
#pragma unroll
    for (int m = 0; m < 4; ++m)
#pragma unroll
        for (int n = 0; n < 2; ++n) acc[m][n] = (f32x4){0.f, 0.f, 0.f, 0.f};

#pragma unroll
    for (int ks = 0; ks < 8; ++ks) {
        ushort* Bcur = (ks & 1) ? Bsm1 : Bsm0;
        ushort* Bnxt = (ks & 1) ? Bsm0 : Bsm1;
        int k0v = ks*32;
        uint4 breg[2];
        if (ks < 7) {
#pragma unroll
            for (int q = 0; q < 2; ++q) {
                int v = t + 512*q;
                int n = v >> 2, c = v & 3;
                breg[q] = *(const uint4*)&W116[n*256 + (k0v + 32) + c*8];
            }
        }
        bf16x8 af[4], bfr[2];
#pragma unroll
        for (int m = 0; m < 4; ++m)
            af[m] = *(const bf16x8*)&Ash[(m*16 + li)*256 + ((k0v + g*8) ^ xs)];
#pragma unroll
        for (int n = 0; n < 2; ++n)
            bfr[n] = *(const bf16x8*)&Bcur[(w*32 + n*16 + li)*40 + g*8];
#pragma unroll
        for (int m = 0; m < 4; ++m)
#pragma unroll
            for (int n = 0; n < 2; ++n)
                acc[m][n] = __builtin_amdgcn_mfma_f32_16x16x32_bf16(af[m], bfr[n], acc[m][n], 0, 0, 0);
        if (ks < 7) {
#pragma unroll
            for (int q = 0; q < 2; ++q) {
                int v = t + 512*q;
                int n = v >> 2, c = v & 3;
                *(uint4*)&Bnxt[n*40 + c*8] = breg[q];
            }
        }
        __syncthreads();
    }

    // ---- sump partial: sum_{j in block, j!=0} Ev_j * sem[j][d] ----
    {
        int qq = t >> 5, c8 = t & 31;           // 16 groups x 4 rows
        float p[8];
#pragma unroll
        for (int i = 0; i < 8; ++i) p[i] = 0.f;
#pragma unroll
        for (int rr = 0; rr < 4; ++rr) {
            int r = qq*4 + rr;
            float ev = EvL[r];
            uint4 uv = *(const uint4*)&Ash[r*256 + ((c8*8) ^ ((r & 7) << 3))];
            p[0] += ev * bflo(uv.x); p[1] += ev * bfhi(uv.x);
            p[2] += ev * bflo(uv.y); p[3] += ev * bfhi(uv.y);
            p[4] += ev * bflo(uv.z); p[5] += ev * bfhi(uv.z);
            p[6] += ev * bflo(uv.w); p[7] += ev * bfhi(uv.w);
        }
        *(float4*)&sumred[qq*256 + c8*8]     = (float4){p[0], p[1], p[2], p[3]};
        *(float4*)&sumred[qq*256 + c8*8 + 4] = (float4){p[4], p[5], p[6], p[7]};
    }
    __syncthreads();
    if (t < 256) {
        float sp = 0.f;
#pragma unroll
        for (int qq = 0; qq < 16; ++qq) sp += sumred[qq*256 + t];
        sump[(long)blockIdx.x*256 + t] = sp;
    }

    // ---- direct-store epilogue (no LDS repack, no extra barriers) ----
    float v1v[2], v2v[2], bzv[2];
#pragma unroll
    for (int n = 0; n < 2; ++n) {
        int col = w*32 + n*16 + li;
        v1v[n] = v1[col];
        v2v[n] = v2b[b*256 + col];
        bzv[n] = bfz[col];
    }
#pragma unroll
    for (int m = 0; m < 4; ++m) {
#pragma unroll
        for (int reg = 0; reg < 4; ++reg) {
            int row = m*16 + g*4 + reg;
            float ca = cAs[row], cb = cBs[row];
            int irow = i0 + row;
#pragma unroll
            for (int n = 0; n < 2; ++n) {
                int col = w*32 + n*16 + li;
                float sel = (irow == 0) ? 0.f : v2v[n];
                float val = acc[m][n][reg] + ca*v1v[n] + cb*sel + bzv[n];
                if (irow == 0) row0pre[b*256 + col] = val;   // pre-ReLU, no v0 term
                out[(rowbase + row)*256 + col] = fmaxf(val, 0.f);
            }
        }
    }
}

// ============ K4: fixup row i=0 of each batch ============
__global__ __launch_bounds__(256) void k_fix(
    const float* __restrict__ sump, const float* __restrict__ fv,
    const float* __restrict__ W2t, const float* __restrict__ row0pre,
    float* __restrict__ out)
{
    int b = blockIdx.x, t = threadIdx.x;
    __shared__ float svsh[256];
    __shared__ float redF[256];
    float a = 0.f;
#pragma unroll
    for (int p = 0; p < 8; ++p) a += sump[(long)(b*8 + p)*256 + t];
    svsh[t] = a;
    redF[t] = fv[b*512 + t] + fv[b*512 + 256 + t];
    __syncthreads();
    for (int s2 = 128; s2 > 0; s2 >>= 1) {
        if (t < s2) redF[t] += redF[t + s2];
        __syncthreads();
    }
    float invF = 1.0f / redF[0];
    float a0 = 0.f;
#pragma unroll 16
    for (int d = 0; d < 256; ++d) a0 += W2t[d*256 + t] * svsh[d];
    out[((long)b*512)*256 + t] = fmaxf(row0pre[b*256 + t] - invF*a0, 0.f);
}

extern "C" void kernel_launch(void* const* d_in, const int* in_sizes, int n_in,
                              void* d_out, int out_size, void* d_ws, size_t ws_size,
                              hipStream_t stream) {
    const float* input   = (const float*)d_in[0];
    const float* Wp      = (const float*)d_in[1];
    const float* bp      = (const float*)d_in[2];
    const float* Wbil    = (const float*)d_in[3];
    const float* bbil    = (const float*)d_in[4];
    const float* Wfi     = (const float*)d_in[5];
    const float* bfi     = (const float*)d_in[6];
    const float* exparam = (const float*)d_in[7];
    const float* Wfz     = (const float*)d_in[8];
    const float* bfz     = (const float*)d_in[9];
    float* ws  = (float*)d_ws;
    float* out = (float*)d_out;

    ushort* Qt16  = (ushort*)(ws + OFF_QT16);
    ushort* W116  = (ushort*)(ws + OFF_W116);
    float*  W2t   = ws + OFF_W2T;
    float*  v1    = ws + OFF_V1;
    float*  c1    = ws + OFF_C1;
    float*  c0    = ws + OFF_C0;
    float*  Ev    = ws + OFF_EV;
    float*  fv    = ws + OFF_FV;
    float*  sump  = ws + OFF_SUMP;
    float*  v2b   = ws + OFF_V2B;
    float*  row0p = ws + OFF_ROW0;

    k0<<<256, 256, 0, stream>>>(Wp, bp, Wbil, Wfz, exparam, Qt16, W116, W2t, v1, c1, c0);
    k_rowstats<<<ROWS_/64, 512, 0, stream>>>(input, Qt16, c1, c0, Wfi, bbil, bfi, W2t, Ev, fv, v2b);
    k_final<<<ROWS_/64, 512, 0, stream>>>(input, W116, v1, v2b, Ev, fv, bfz, sump, row0p, out);
    k_fix<<<B_, 256, 0, stream>>>(sump, fv, W2t, row0p, out);
}